// Round 14
// baseline (822.831 us; speedup 1.0000x reference)
//
#include <hip/hip_runtime.h>
#include <hip/hip_bf16.h>

typedef unsigned short u16;
typedef unsigned int u32;
typedef unsigned long long u64;
typedef __attribute__((ext_vector_type(8))) short short8;
typedef __attribute__((ext_vector_type(4))) float f32x4;

#define TOKENS 4096
#define HDIM 2048
#define NEXP 16
#define IDIM 1024
#define ISH 2048
#define NCHUNK 128  // 8192 route entries / 64 lanes

// merged GEMM work lists (16-item supertiles)
#define GUITEMS 1152  // 72 supertiles = 8 XCD groups x 9 (y-panels of 128)
#define DITEMS 1024   // 64 supertiles = 8 x 8 (y-panels of 128)

#define AS1(p) ((const __attribute__((address_space(1))) u32*)(p))
#define AS3(p) ((__attribute__((address_space(3))) u32*)(p))

__device__ __forceinline__ u16 f2b(float f) {
    u32 u = __float_as_uint(f);
    u32 r = u + 0x7fffu + ((u >> 16) & 1u);
    return (u16)(r >> 16);
}

// supertile round-robin: supertile s -> XCD s%8
__device__ __forceinline__ int item_index(int bid) {
    int x = bid & 7, j = bid >> 3;
    return ((x + 8 * (j >> 4)) << 4) | (j & 15);
}

// ---------------- routing: 1 wave per token; ALSO emits x_bf (fused convert) --
__global__ __launch_bounds__(256) void route_kernel(const float* __restrict__ x,
                                                    const float* __restrict__ cent,
                                                    const float* __restrict__ bias,
                                                    u16* __restrict__ xb,
                                                    int* __restrict__ top_e,
                                                    float* __restrict__ top_w) {
    __shared__ alignas(16) float cs[8 * 2048];  // 64KB: 8 experts per phase
    int lane = threadIdx.x & 63;
    int wv = threadIdx.x >> 6;
    int t = blockIdx.x * 4 + wv;
    const float4* xp4 = (const float4*)(x + (size_t)t * HDIM);
    float4 xr[8];
#pragma unroll
    for (int i = 0; i < 8; i++) xr[i] = xp4[lane + 64 * i];
    u16* xbp = xb + (size_t)t * HDIM;
#pragma unroll
    for (int i = 0; i < 8; i++) {
        u32 lo = (u32)f2b(xr[i].x) | ((u32)f2b(xr[i].y) << 16);
        u32 hi = (u32)f2b(xr[i].z) | ((u32)f2b(xr[i].w) << 16);
        uint2 o = make_uint2(lo, hi);
        *(uint2*)(xbp + (size_t)(lane + 64 * i) * 4) = o;
    }
    float aff[16];
#pragma unroll
    for (int ph = 0; ph < 2; ph++) {
        if (ph) __syncthreads();
        const float* sbase = cent + (size_t)(ph * 8 + wv * 2) * HDIM;
        float* dbase = cs + (size_t)wv * 2 * HDIM;
#pragma unroll
        for (int i = 0; i < 16; i++) {
            __builtin_amdgcn_global_load_lds(AS1(sbase + i * 256 + lane * 4),
                                             AS3(dbase + i * 256), 16, 0, 0);
        }
        __syncthreads();
#pragma unroll
        for (int e = 0; e < 8; e++) {
            const float4* cp = (const float4*)cs + (size_t)e * 512;
            float s = 0.f;
#pragma unroll
            for (int i = 0; i < 8; i++) {
                float4 cv = cp[lane + 64 * i];
                s += xr[i].x * cv.x;
                s += xr[i].y * cv.y;
                s += xr[i].z * cv.z;
                s += xr[i].w * cv.w;
            }
#pragma unroll
            for (int off = 32; off > 0; off >>= 1) s += __shfl_xor(s, off, 64);
            aff[ph * 8 + e] = 1.f / (1.f + expf(-s));
        }
    }
    float b0 = -1e30f, b1 = -1e30f, a0 = 0.f, a1 = 0.f;
    int e0 = -1, e1 = -1;
#pragma unroll
    for (int e = 0; e < 16; e++) {
        float v = aff[e] + bias[e];
        if (v > b0) {
            b1 = b0; e1 = e0; a1 = a0;
            b0 = v; e0 = e; a0 = aff[e];
        } else if (v > b1) {
            b1 = v; e1 = e; a1 = aff[e];
        }
    }
    float inv = 1.f / (a0 + a1 + 1e-9f);
    if (lane == 0) {
        top_e[2 * t] = e0; top_w[2 * t] = a0 * inv;
        top_e[2 * t + 1] = e1; top_w[2 * t + 1] = a1 * inv;
    }
}

// ---------------- build: histogram + scan + work-item lists + scatter ----------
__global__ __launch_bounds__(1024) void build_kernel(
    const int* __restrict__ top_e, const float* __restrict__ top_w,
    int* __restrict__ counts, int* __restrict__ offsets, int* __restrict__ itemsGU,
    int* __restrict__ itemsD, int* __restrict__ list_tok, int* __restrict__ tok2slot) {
    __shared__ int cnt[NCHUNK][16];
    __shared__ int offs_s[16];
    __shared__ int totals[16];
    __shared__ int guPref[16], dPref[16];
    int tid = threadIdx.x;
    int lane = tid & 63, wv = tid >> 6;  // 16 waves
    for (int i = tid; i < GUITEMS; i += 1024) itemsGU[i] = -1;
    for (int i = tid; i < DITEMS; i += 1024) itemsD[i] = -1;
    for (int c = wv; c < NCHUNK; c += 16) {
        int v = top_e[c * 64 + lane];
#pragma unroll
        for (int e = 0; e < 16; e++) {
            u64 m = __ballot(v == e);
            if (lane == 0) cnt[c][e] = (int)__popcll(m);
        }
    }
    __syncthreads();
    if (tid < 16) {
        int s = 0;
        for (int c = 0; c < NCHUNK; c++) s += cnt[c][tid];
        totals[tid] = s;
        counts[tid] = s;
    }
    __syncthreads();
    if (tid == 0) {
        int r = 0, g = 0, d = 0;
        for (int e = 0; e < 16; e++) {
            offs_s[e] = r;
            offsets[e] = r;
            r += totals[e];
            guPref[e] = g;
            g += ((totals[e] + 127) >> 7) * 8;   // 8 y128 panels (IDIM)
            dPref[e] = d;
            d += ((totals[e] + 255) >> 8) * 16;  // 16 y128 panels (HDIM)
        }
    }
    if (tid < 512) {  // GU shared: 32 mtiles x 16 y128 = 512 items
        int i = tid;
        int g = i >> 4, s = i & 15;
        int y0 = (g >> 3) << 2, m0 = (g & 7) << 2;
        itemsGU[i] = ((m0 + (s >> 2)) << 8) | (y0 + (s & 3));
    }
    if (tid < 256) {  // D shared: 16 mtiles x 16 y128 = 256 items
        int i = tid;
        int g = i >> 4, s = i & 15;
        int y0 = (g >> 2) << 2, m0 = (g & 3) << 2;
        itemsD[i] = ((m0 + (s >> 2)) << 8) | (y0 + (s & 3));
    }
    __syncthreads();
    if (tid < 16) {
        int e = tid;
        int tA = (totals[e] + 127) >> 7;
        int p = 512 + guPref[e];
        for (int y0 = 0; y0 < 8; y0 += 4)
            for (int m = 0; m < tA; m++)
                for (int dy = 0; dy < 4; dy++)
                    itemsGU[p++] = (1 << 28) | (e << 20) | (m << 8) | (y0 + dy);
        int tB = (totals[e] + 255) >> 8;
        p = 256 + dPref[e];
        for (int y0 = 0; y0 < 16; y0 += 4)
            for (int m = 0; m < tB; m++)
                for (int dy = 0; dy < 4; dy++)
                    itemsD[p++] = (1 << 28) | (e << 20) | (m << 8) | (y0 + dy);
        int r = offs_s[e];
        for (int c = 0; c < NCHUNK; c++) {
            int v = cnt[c][e];
            cnt[c][e] = r;
            r += v;
        }
    }
    __syncthreads();
    for (int c = wv; c < NCHUNK; c += 16) {
        int i = c * 64 + lane;
        int v = top_e[i];
        int rank = 0;
#pragma unroll
        for (int e = 0; e < 16; e++) {
            u64 m = __ballot(v == e);
            if (v == e) rank = (int)__popcll(m & ((1ull << lane) - 1ull));
        }
        int slot = cnt[c][v] + rank;
        list_tok[slot] = i >> 1;
        tok2slot[i] = slot;
    }
}

// ================= MAIN PATH =================
// ALL weight conversions in ONE dispatch (flat grid).
// LDS overhaul vs r13: (1) write-col XOR swizzle (kr ^ 2*(ng&3)) drops the
// 8-way ds_write_u16 bank conflict to 2-way (free); (2) read side becomes ONE
// ds_read_b128 + cndmask word-unpermute (was 8 scalar ds_read_u16); (3) Ls
// double-buffered -> 1 barrier/iter (was 2).
__global__ __launch_bounds__(256) void conv_all_kernel(
    const float* __restrict__ wgs, const float* __restrict__ wus,
    const float* __restrict__ wds, const float* __restrict__ wg,
    const float* __restrict__ wu, const float* __restrict__ wd, u16* __restrict__ Wt_gs,
    u16* __restrict__ Wt_us, u16* __restrict__ Wt_ds, u16* __restrict__ Wt_g,
    u16* __restrict__ Wt_u, u16* __restrict__ Wt_d) {
    int id = blockIdx.x;
    const float* Wm;
    u16* Wtm;
    int K, N, nt, kc;
    if (id < 768) {
        K = 2048; N = 2048;
        int seg = id >> 8, r = id & 255;
        nt = r & 31; kc = r >> 5;
        if (seg == 0) { Wm = wgs; Wtm = Wt_gs; }
        else if (seg == 1) { Wm = wus; Wtm = Wt_us; }
        else { Wm = wds; Wtm = Wt_ds; }
    } else if (id < 4864) {
        K = 2048; N = 1024;
        int r = id - 768;
        int m = r >> 11;
        r &= 2047;
        int e = r >> 7;
        r &= 127;
        nt = r & 15; kc = r >> 4;
        size_t off = (size_t)e * 2048 * 1024;
        if (m == 0) { Wm = wg + off; Wtm = Wt_g + off; }
        else { Wm = wu + off; Wtm = Wt_u + off; }
    } else {
        K = 1024; N = 2048;
        int r = id - 4864;
        int e = r >> 7;
        r &= 127;
        nt = r & 31; kc = r >> 5;
        size_t off = (size_t)e * 1024 * 2048;
        Wm = wd + off; Wtm = Wt_d + off;
    }
    int ksB = K >> 5;
    __shared__ alignas(16) u16 Ls[2][2560];  // 2 x 64 rows x 40 (double buffer)
    int t = threadIdx.x;
    int kr = t >> 3, ng = t & 7;
    int nn = t >> 2, seg2 = t & 3;
    int g = seg2 ^ ((nn >> 2) & 3);
    int wcol = kr ^ (2 * (ng & 3));  // write swizzle: rows 8ng+l spread banks
    int sh = (nn >> 3) & 3;          // reader's u32-word unpermute selector
#pragma unroll
    for (int s = 0; s < 8; s++) {
        u16* L = Ls[s & 1];
        int kb = kc * 256 + s * 32;
        const float* src = Wm + (size_t)(kb + kr) * N + nt * 64 + ng * 8;
        float4 f0 = *(const float4*)src;
        float4 f1 = *(const float4*)(src + 4);
        const float* p0 = (const float*)&f0;
        const float* p1 = (const float*)&f1;
#pragma unroll
        for (int l = 0; l < 4; l++) L[(8 * ng + l) * 40 + wcol] = f2b(p0[l]);
#pragma unroll
        for (int l = 0; l < 4; l++) L[(8 * ng + 4 + l) * 40 + wcol] = f2b(p1[l]);
        __syncthreads();
        uint4 q = *(const uint4*)(L + nn * 40 + g * 8);
        // undo the write swizzle: output word w = q[w ^ sh]
        u32 t0 = (sh & 1) ? q.y : q.x;
        u32 t1 = (sh & 1) ? q.x : q.y;
        u32 t2 = (sh & 1) ? q.w : q.z;
        u32 t3 = (sh & 1) ? q.z : q.w;
        uint4 o = make_uint4((sh & 2) ? t2 : t0, (sh & 2) ? t3 : t1,
                             (sh & 2) ? t0 : t2, (sh & 2) ? t1 : t3);
        *(uint4*)(Wtm + (size_t)(nt * ksB + (kb >> 5)) * 2048 + t * 8) = o;
    }
}

// merged fused gate+up: M=128, N=128 per matrix, BK=64, 8 waves. (r11/r13
// verified: 219us, 2-phase structural ceiling for this geometry.)
__global__ __launch_bounds__(512, 4) void gemm_gateup(
    const u16* __restrict__ A, const u16* __restrict__ BgS, const u16* __restrict__ BuS,
    const u16* __restrict__ BgR, const u16* __restrict__ BuR, u16* __restrict__ hS,
    u16* __restrict__ hR, const int* __restrict__ counts, const int* __restrict__ offsets,
    const int* __restrict__ list_tok, const int* __restrict__ items) {
    int it = items[item_index(blockIdx.x)];
    if (it < 0) return;
    int routed = (it >> 28) & 1;
    int e = (it >> 20) & 15;
    int m0 = ((it >> 8) & 4095) * 128;
    int yb = it & 255;  // y-panel of 128
    int cnt, base, Nout;
    u16* hout;
    const u16 *BgBase, *BuBase;
    if (routed) {
        cnt = counts[e];
        base = offsets[e];
        Nout = IDIM;
        size_t off = (size_t)e * HDIM * IDIM;
        BgBase = BgR + off;
        BuBase = BuR + off;
        hout = hR;
    } else {
        cnt = TOKENS;
        base = 0;
        Nout = ISH;
        BgBase = BgS;
        BuBase = BuS;
        hout = hS;
    }
    const int nk = HDIM >> 6;  // BK=64 steps
    __shared__ alignas(16) u16 smem[24576];  // As 16KB | Bgs 16KB | Bus 16KB
    u16* As = smem;
    u16* Bgs = smem + 8192;
    u16* Bus = smem + 16384;
    float* us = (float*)smem;  // epilogue reuse (32KB of the 48KB)
    int tid = threadIdx.x;
    int lane = tid & 63, wv = tid >> 6;  // 8 waves
    int wl = wv & 3, mat = wv >> 2;      // mat: 0=gate, 1=up
    int quad = lane >> 4, mr = lane & 15;
    int gk = (tid & 3) ^ ((tid >> 4) & 3);
    int mg0 = min(m0 + (tid >> 2), cnt - 1);
    size_t sr0 = routed ? (size_t)list_tok[base + mg0] : (size_t)mg0;
    const u16* ap0 = A + sr0 * HDIM + gk * 8;  // thread stages A row tid>>2
    size_t bstr = (size_t)(HDIM >> 5) * 2048;  // per-n64-block stride
    int t4 = tid & 255;
    const u16* Bsel = mat ? BuBase : BgBase;
    const u16* bsrc0 = Bsel + (size_t)(2 * yb) * bstr + (size_t)t4 * 8;  // h=0
    const u16* bsrc1 = bsrc0 + bstr;                                     // h=1
    u16* bb = mat ? Bus : Bgs;
    u16* bdst = bb + wl * 512;  // wave-uniform base (+HW lane*16B)
    u16* adst = As + wv * 512;
    int xq = quad ^ ((mr >> 2) & 3);
    f32x4 acc[2][8];
#pragma unroll
    for (int i = 0; i < 2; i++)
#pragma unroll
        for (int j = 0; j < 8; j++) acc[i][j] = (f32x4)0.f;

    for (int ks = 0; ks < nk; ks++) {
        __syncthreads();
        __builtin_amdgcn_global_load_lds(AS1(ap0), AS3(adst), 16, 0, 0);
        __builtin_amdgcn_global_load_lds(AS1(ap0 + 32), AS3(adst + 4096), 16, 0, 0);
        __builtin_amdgcn_global_load_lds(AS1(bsrc0), AS3(bdst), 16, 0, 0);
        __builtin_amdgcn_global_load_lds(AS1(bsrc0 + 2048), AS3(bdst + 2048), 16, 0, 0);
        __builtin_amdgcn_global_load_lds(AS1(bsrc1), AS3(bdst + 4096), 16, 0, 0);
        __builtin_amdgcn_global_load_lds(AS1(bsrc1 + 2048), AS3(bdst + 6144), 16, 0, 0);
        ap0 += 64;
        bsrc0 += 4096;
        bsrc1 += 4096;
        __syncthreads();
#pragma unroll
        for (int c = 0; c < 2; c++) {
            short8 a0 = *(const short8*)(As + c * 4096 + ((32 * wl + mr) * 4 + xq) * 8);
            short8 a1 = *(const short8*)(As + c * 4096 + ((32 * wl + 16 + mr) * 4 + xq) * 8);
#pragma unroll
            for (int j = 0; j < 8; j++) {
                int h = j >> 2, jj = j & 3;
                short8 b = *(const short8*)(bb + h * 4096 + c * 2048 +
                                            (64 * jj + mr * 4 + xq) * 8);
                acc[0][j] = __builtin_amdgcn_mfma_f32_16x16x32_bf16(a0, b, acc[0][j], 0, 0, 0);
                acc[1][j] = __builtin_amdgcn_mfma_f32_16x16x32_bf16(a1, b, acc[1][j], 0, 0, 0);
            }
        }
    }
    // epilogue: two half-passes of 64 cols through the 32KB us buffer.
#pragma unroll
    for (int p = 0; p < 2; p++) {
        __syncthreads();
        if (mat == 1) {
#pragma unroll
            for (int i = 0; i < 2; i++)
#pragma unroll
                for (int jj = 0; jj < 4; jj++)
#pragma unroll
                    for (int r = 0; r < 4; r++) {
                        int row = 32 * wl + 16 * i + quad * 4 + r;
                        us[row * 64 + 16 * jj + mr] = acc[i][4 * p + jj][r];
                    }
        }
        __syncthreads();
        if (mat == 0) {
#pragma unroll
            for (int i = 0; i < 2; i++)
#pragma unroll
                for (int jj = 0; jj < 4; jj++)
#pragma unroll
                    for (int r = 0; r < 4; r++) {
                        int row = 32 * wl + 16 * i + quad * 4 + r;
                        int m = m0 + row;
                        if (m < cnt) {
                            float gv = acc[i][4 * p + jj][r];
                            float uv = us[row * 64 + 16 * jj + mr];
                            float h = gv / (1.f + expf(-gv)) * uv;
                            int n = yb * 128 + p * 64 + 16 * jj + mr;
                            hout[(size_t)(base + m) * Nout + n] = f2b(h);
                        }
                    }
        }
    }
}

// merged down GEMM: M=256, N=128, BK=64, 8 waves (512 threads). (r13 verified)
__global__ __launch_bounds__(512, 4) void gemm_down(
    const u16* __restrict__ hS, const u16* __restrict__ hR, const u16* __restrict__ BdS,
    const u16* __restrict__ BdR, float* __restrict__ out, float* __restrict__ rd,
    const int* __restrict__ counts, const int* __restrict__ offsets,
    const int* __restrict__ items) {
    int it = items[item_index(blockIdx.x)];
    if (it < 0) return;
    int routed = (it >> 28) & 1;
    int e = (it >> 20) & 15;
    int m0 = ((it >> 8) & 4095) * 256;
    int yb = it & 255;  // y-panel of 128
    int cnt, base, Kd;
    const u16 *A, *B;
    float* outp;
    if (routed) {
        cnt = counts[e];
        base = offsets[e];
        Kd = IDIM;
        A = hR;
        B = BdR + (size_t)e * IDIM * HDIM;
        outp = rd;
    } else {
        cnt = TOKENS;
        base = 0;
        Kd = ISH;
        A = hS;
        B = BdS;
        outp = out;
    }
    int nk = Kd >> 6;  // BK=64
    __shared__ alignas(16) u16 As[2 * 8192];  // 32KB: chunk c at c*8192 (256r x 32k)
    __shared__ alignas(16) u16 Bs[2 * 4096];  // 16KB: half h at h*4096, chunk c +c*2048
    int tid = threadIdx.x;
    int lane = tid & 63, wv = tid >> 6;  // 8 waves
    int wl = wv & 3, nh = wv >> 2;       // m-group / n-half
    int quad = lane >> 4, mr = lane & 15;
    int gk = (tid & 3) ^ ((tid >> 4) & 3);
    int mg0 = base + min(m0 + (tid >> 2), cnt - 1);
    int mg1 = base + min(m0 + 128 + (tid >> 2), cnt - 1);
    const u16* ap0 = A + (size_t)mg0 * Kd + gk * 8;
    const u16* ap1 = A + (size_t)mg1 * Kd + gk * 8;
    size_t bstr = (size_t)(Kd >> 5) * 2048;
    int grp = tid >> 8;  // n-half this thread stages (wave-uniform)
    int t4 = tid & 255;
    const u16* bp = B + (size_t)(2 * yb + grp) * bstr + (size_t)t4 * 8;
    u16* bdst = Bs + grp * 4096 + wl * 512;  // wave-uniform base
    int xq = quad ^ ((mr >> 2) & 3);
    f32x4 acc[4][4];
#pragma unroll
    for (int i = 0; i < 4; i++)
#pragma unroll
        for (int j = 0; j < 4; j++) acc[i][j] = (f32x4)0.f;

    for (int ks = 0; ks < nk; ks++) {
        __syncthreads();
        __builtin_amdgcn_global_load_lds(AS1(ap0), AS3(As + wv * 512), 16, 0, 0);
        __builtin_amdgcn_global_load_lds(AS1(ap0 + 32), AS3(As + 8192 + wv * 512), 16, 0, 0);
        __builtin_amdgcn_global_load_lds(AS1(ap1), AS3(As + 4096 + wv * 512), 16, 0, 0);
        __builtin_amdgcn_global_load_lds(AS1(ap1 + 32), AS3(As + 12288 + wv * 512), 16, 0, 0);
        __builtin_amdgcn_global_load_lds(AS1(bp), AS3(bdst), 16, 0, 0);
        __builtin_amdgcn_global_load_lds(AS1(bp + 2048), AS3(bdst + 2048), 16, 0, 0);
        ap0 += 64; ap1 += 64; bp += 4096;
        __syncthreads();
#pragma unroll
        for (int c = 0; c < 2; c++) {
            short8 a0 = *(const short8*)(As + c * 8192 + ((64 * wl + 0 + mr) * 4 + xq) * 8);
            short8 a1 = *(const short8*)(As + c * 8192 + ((64 * wl + 16 + mr) * 4 + xq) * 8);
            short8 a2 = *(const short8*)(As + c * 8192 + ((64 * wl + 32 + mr) * 4 + xq) * 8);
            short8 a3 = *(const short8*)(As + c * 8192 + ((64 * wl + 48 + mr) * 4 + xq) * 8);
#pragma unroll
            for (int j = 0; j < 4; j++) {
                short8 b = *(const short8*)(Bs + nh * 4096 + c * 2048 +
                                            (64 * j + mr * 4 + xq) * 8);
                acc[0][j] = __builtin_amdgcn_mfma_f32_16x16x32_bf16(a0, b, acc[0][j], 0, 0, 0);
                acc[1][j] = __builtin_amdgcn_mfma_f32_16x16x32_bf16(a1, b, acc[1][j], 0, 0, 0);
                acc[2][j] = __builtin_amdgcn_mfma_f32_16x16x32_bf16(a2, b, acc[2][j], 0, 0, 0);
                acc[3][j] = __builtin_amdgcn_mfma_f32_16x16x32_bf16(a3, b, acc[3][j], 0, 0, 0);
            }
        }
    }

#pragma unroll
    for (int i = 0; i < 4; i++)
#pragma unroll
        for (int j = 0; j < 4; j++)
#pragma unroll
            for (int r = 0; r < 4; r++) {
                int m = m0 + 64 * wl + 16 * i + quad * 4 + r;
                if (m >= cnt) continue;
                int n = yb * 128 + nh * 64 + 16 * j + mr;
                float v = acc[i][j][r];
                if (routed) {
                    outp[(size_t)(base + m) * HDIM + n] = v;  // per-slot, no atomics
                } else {
                    outp[(size_t)m * HDIM + n] = 0.1f * v;
                }
            }
}

// ---------------- combine: out[t] += w0*rd[slot0] + w1*rd[slot1] ----------------
__global__ __launch_bounds__(256) void combine_kernel(float* __restrict__ out,
                                                      const float* __restrict__ rd,
                                                      const int* __restrict__ tok2slot,
                                                      const float* __restrict__ top_w) {
    int t = blockIdx.x;
    int s0 = tok2slot[2 * t], s1 = tok2slot[2 * t + 1];
    float w0 = top_w[2 * t], w1 = top_w[2 * t + 1];
    const float4* r0 = (const float4*)(rd + (size_t)s0 * HDIM);
    const float4* r1 = (const float4*)(rd + (size_t)s1 * HDIM);
    float4* op = (float4*)(out + (size_t)t * HDIM);
#pragma unroll
    for (int k = 0; k < 2; k++) {
        int c = threadIdx.x + k * 256;
        float4 o = op[c];
        float4 a = r0[c];
        float4 b = r1[c];
        o.x += w0 * a.x + w1 * b.x;
        o.y += w0 * a.y + w1 * b.y;
        o.z += w0 * a.z + w1 * b.z;
        o.w += w0 * a.w + w1 * b.w;
        op[c] = o;
    }
}

extern "C" void kernel_launch(void* const* d_in, const int* in_sizes, int n_in,
                              void* d_out, int out_size, void* d_ws, size_t ws_size,
                              hipStream_t stream) {
    const float* x = (const float*)d_in[0];
    const float* cent = (const float*)d_in[1];
    const float* bias = (const float*)d_in[2];
    const float* wgs = (const float*)d_in[3];
    const float* wus = (const float*)d_in[4];
    const float* wds = (const float*)d_in[5];
    const float* wg = (const float*)d_in[6];
    const float* wu = (const float*)d_in[7];
    const float* wd = (const float*)d_in[8];
    float* out = (float*)d_out;
    char* ws = (char*)d_ws;

    size_t off_wtgs = 0;
    size_t off_wtus = off_wtgs + (size_t)HDIM * ISH * 2;
    size_t off_wtds = off_wtus + (size_t)HDIM * ISH * 2;
    size_t off_wtg = off_wtds + (size_t)ISH * HDIM * 2;
    size_t off_wtu = off_wtg + (size_t)NEXP * HDIM * IDIM * 2;
    size_t off_wtd = off_wtu + (size_t)NEXP * HDIM * IDIM * 2;
    size_t off_xbf = off_wtd + (size_t)NEXP * IDIM * HDIM * 2;
    size_t off_hsh = off_xbf + (size_t)TOKENS * HDIM * 2;
    size_t off_hrt = off_hsh + (size_t)TOKENS * ISH * 2;
    size_t off_meta = off_hrt + (size_t)2 * TOKENS * IDIM * 2;
    size_t need = off_meta + (1 << 20);
    if (ws_size < need) return;  // main path verified present in round 2

    u16* Wt_gs = (u16*)(ws + off_wtgs);
    u16* Wt_us = (u16*)(ws + off_wtus);
    u16* Wt_ds = (u16*)(ws + off_wtds);
    u16* Wt_g = (u16*)(ws + off_wtg);
    u16* Wt_u = (u16*)(ws + off_wtu);
    u16* Wt_d = (u16*)(ws + off_wtd);
    u16* x_bf = (u16*)(ws + off_xbf);
    u16* h_sh = (u16*)(ws + off_hsh);
    u16* h_rt = (u16*)(ws + off_hrt);
    // rd (67 MB, f32 [8192][2048]) at off_wtg: overlaps routed gate/up weights
    // only; their last reader (merged gateup) completes before gemm_down writes
    // rd. conv_all rewrites the weights next iteration.
    float* rd = (float*)(ws + off_wtg);
    int* counts = (int*)(ws + off_meta);
    int* offsets = counts + 16;
    int* itemsGU = offsets + 16;
    int* itemsD = itemsGU + GUITEMS;
    int* tok2slot = itemsD + DITEMS;
    int* top_e = tok2slot + 2 * TOKENS;
    float* top_w = (float*)(top_e + 2 * TOKENS);
    int* list_tok = (int*)(top_w + 2 * TOKENS);

    route_kernel<<<TOKENS / 4, 256, 0, stream>>>(x, cent, bias, x_bf, top_e, top_w);
    build_kernel<<<1, 1024, 0, stream>>>(top_e, top_w, counts, offsets, itemsGU, itemsD,
                                         list_tok, tok2slot);
    conv_all_kernel<<<6912, 256, 0, stream>>>(wgs, wus, wds, wg, wu, wd, Wt_gs, Wt_us,
                                              Wt_ds, Wt_g, Wt_u, Wt_d);
    gemm_gateup<<<GUITEMS, 512, 0, stream>>>(x_bf, Wt_gs, Wt_us, Wt_g, Wt_u, h_sh, h_rt,
                                             counts, offsets, list_tok, itemsGU);
    gemm_down<<<DITEMS, 512, 0, stream>>>(h_sh, h_rt, Wt_ds, Wt_d, out, rd, counts,
                                          offsets, itemsD);
    combine_kernel<<<TOKENS, 256, 0, stream>>>(out, rd, tok2slot, top_w);
}

// Round 15
// 813.658 us; speedup vs baseline: 1.0113x; 1.0113x over previous
//
#include <hip/hip_runtime.h>
#include <hip/hip_bf16.h>

typedef unsigned short u16;
typedef unsigned int u32;
typedef unsigned long long u64;
typedef __attribute__((ext_vector_type(8))) short short8;
typedef __attribute__((ext_vector_type(4))) float f32x4;

#define TOKENS 4096
#define HDIM 2048
#define NEXP 16
#define IDIM 1024
#define ISH 2048
#define NCHUNK 128  // 8192 route entries / 64 lanes

// merged GEMM work lists (16-item supertiles)
#define GUITEMS 1152  // 72 supertiles = 8 XCD groups x 9 (y-panels of 128)
#define DITEMS 1024   // 64 supertiles = 8 x 8 (y-panels of 128)

#define AS1(p) ((const __attribute__((address_space(1))) u32*)(p))
#define AS3(p) ((__attribute__((address_space(3))) u32*)(p))

__device__ __forceinline__ u16 f2b(float f) {
    u32 u = __float_as_uint(f);
    u32 r = u + 0x7fffu + ((u >> 16) & 1u);
    return (u16)(r >> 16);
}

// supertile round-robin: supertile s -> XCD s%8
__device__ __forceinline__ int item_index(int bid) {
    int x = bid & 7, j = bid >> 3;
    return ((x + 8 * (j >> 4)) << 4) | (j & 15);
}

// ---------------- routing: 8 waves / 8 tokens per block (512 thr) ------------
// One full-occupancy round (512 blocks, 2/CU, 16 waves/CU) instead of two;
// cent staging halves (each wave stages ONE expert per phase: 8 x 1KB loads).
// Also emits x_bf (fused convert).
__global__ __launch_bounds__(512) void route_kernel(const float* __restrict__ x,
                                                    const float* __restrict__ cent,
                                                    const float* __restrict__ bias,
                                                    u16* __restrict__ xb,
                                                    int* __restrict__ top_e,
                                                    float* __restrict__ top_w) {
    __shared__ alignas(16) float cs[8 * 2048];  // 64KB: 8 experts per phase
    int lane = threadIdx.x & 63;
    int wv = threadIdx.x >> 6;  // 8 waves
    int t = blockIdx.x * 8 + wv;
    const float4* xp4 = (const float4*)(x + (size_t)t * HDIM);
    float4 xr[8];
#pragma unroll
    for (int i = 0; i < 8; i++) xr[i] = xp4[lane + 64 * i];
    u16* xbp = xb + (size_t)t * HDIM;
#pragma unroll
    for (int i = 0; i < 8; i++) {
        u32 lo = (u32)f2b(xr[i].x) | ((u32)f2b(xr[i].y) << 16);
        u32 hi = (u32)f2b(xr[i].z) | ((u32)f2b(xr[i].w) << 16);
        uint2 o = make_uint2(lo, hi);
        *(uint2*)(xbp + (size_t)(lane + 64 * i) * 4) = o;
    }
    float aff[16];
#pragma unroll
    for (int ph = 0; ph < 2; ph++) {
        if (ph) __syncthreads();  // all waves done reading previous phase
        // wave wv stages expert ph*8+wv (8KB = 8 x 1KB wave-loads)
        const float* sbase = cent + (size_t)(ph * 8 + wv) * HDIM;
        float* dbase = cs + (size_t)wv * HDIM;
#pragma unroll
        for (int i = 0; i < 8; i++) {
            __builtin_amdgcn_global_load_lds(AS1(sbase + i * 256 + lane * 4),
                                             AS3(dbase + i * 256), 16, 0, 0);
        }
        __syncthreads();  // drains vmcnt before barrier
#pragma unroll
        for (int e = 0; e < 8; e++) {
            const float4* cp = (const float4*)cs + (size_t)e * 512;
            float s = 0.f;
#pragma unroll
            for (int i = 0; i < 8; i++) {
                float4 cv = cp[lane + 64 * i];
                s += xr[i].x * cv.x;
                s += xr[i].y * cv.y;
                s += xr[i].z * cv.z;
                s += xr[i].w * cv.w;
            }
#pragma unroll
            for (int off = 32; off > 0; off >>= 1) s += __shfl_xor(s, off, 64);
            aff[ph * 8 + e] = 1.f / (1.f + expf(-s));
        }
    }
    float b0 = -1e30f, b1 = -1e30f, a0 = 0.f, a1 = 0.f;
    int e0 = -1, e1 = -1;
#pragma unroll
    for (int e = 0; e < 16; e++) {
        float v = aff[e] + bias[e];
        if (v > b0) {
            b1 = b0; e1 = e0; a1 = a0;
            b0 = v; e0 = e; a0 = aff[e];
        } else if (v > b1) {
            b1 = v; e1 = e; a1 = aff[e];
        }
    }
    float inv = 1.f / (a0 + a1 + 1e-9f);
    if (lane == 0) {
        top_e[2 * t] = e0; top_w[2 * t] = a0 * inv;
        top_e[2 * t + 1] = e1; top_w[2 * t + 1] = a1 * inv;
    }
}

// ---------------- build: histogram + scan + work-item lists + scatter ----------
__global__ __launch_bounds__(1024) void build_kernel(
    const int* __restrict__ top_e, const float* __restrict__ top_w,
    int* __restrict__ counts, int* __restrict__ offsets, int* __restrict__ itemsGU,
    int* __restrict__ itemsD, int* __restrict__ list_tok, int* __restrict__ tok2slot) {
    __shared__ int cnt[NCHUNK][16];
    __shared__ int offs_s[16];
    __shared__ int totals[16];
    __shared__ int guPref[16], dPref[16];
    int tid = threadIdx.x;
    int lane = tid & 63, wv = tid >> 6;  // 16 waves
    for (int i = tid; i < GUITEMS; i += 1024) itemsGU[i] = -1;
    for (int i = tid; i < DITEMS; i += 1024) itemsD[i] = -1;
    for (int c = wv; c < NCHUNK; c += 16) {
        int v = top_e[c * 64 + lane];
#pragma unroll
        for (int e = 0; e < 16; e++) {
            u64 m = __ballot(v == e);
            if (lane == 0) cnt[c][e] = (int)__popcll(m);
        }
    }
    __syncthreads();
    if (tid < 16) {
        int s = 0;
        for (int c = 0; c < NCHUNK; c++) s += cnt[c][tid];
        totals[tid] = s;
        counts[tid] = s;
    }
    __syncthreads();
    if (tid == 0) {
        int r = 0, g = 0, d = 0;
        for (int e = 0; e < 16; e++) {
            offs_s[e] = r;
            offsets[e] = r;
            r += totals[e];
            guPref[e] = g;
            g += ((totals[e] + 127) >> 7) * 8;   // 8 y128 panels (IDIM)
            dPref[e] = d;
            d += ((totals[e] + 255) >> 8) * 16;  // 16 y128 panels (HDIM)
        }
    }
    if (tid < 512) {  // GU shared: 32 mtiles x 16 y128 = 512 items
        int i = tid;
        int g = i >> 4, s = i & 15;
        int y0 = (g >> 3) << 2, m0 = (g & 7) << 2;
        itemsGU[i] = ((m0 + (s >> 2)) << 8) | (y0 + (s & 3));
    }
    if (tid < 256) {  // D shared: 16 mtiles x 16 y128 = 256 items
        int i = tid;
        int g = i >> 4, s = i & 15;
        int y0 = (g >> 2) << 2, m0 = (g & 3) << 2;
        itemsD[i] = ((m0 + (s >> 2)) << 8) | (y0 + (s & 3));
    }
    __syncthreads();
    if (tid < 16) {
        int e = tid;
        int tA = (totals[e] + 127) >> 7;
        int p = 512 + guPref[e];
        for (int y0 = 0; y0 < 8; y0 += 4)
            for (int m = 0; m < tA; m++)
                for (int dy = 0; dy < 4; dy++)
                    itemsGU[p++] = (1 << 28) | (e << 20) | (m << 8) | (y0 + dy);
        int tB = (totals[e] + 255) >> 8;
        p = 256 + dPref[e];
        for (int y0 = 0; y0 < 16; y0 += 4)
            for (int m = 0; m < tB; m++)
                for (int dy = 0; dy < 4; dy++)
                    itemsD[p++] = (1 << 28) | (e << 20) | (m << 8) | (y0 + dy);
        int r = offs_s[e];
        for (int c = 0; c < NCHUNK; c++) {
            int v = cnt[c][e];
            cnt[c][e] = r;
            r += v;
        }
    }
    __syncthreads();
    for (int c = wv; c < NCHUNK; c += 16) {
        int i = c * 64 + lane;
        int v = top_e[i];
        int rank = 0;
#pragma unroll
        for (int e = 0; e < 16; e++) {
            u64 m = __ballot(v == e);
            if (v == e) rank = (int)__popcll(m & ((1ull << lane) - 1ull));
        }
        int slot = cnt[c][v] + rank;
        list_tok[slot] = i >> 1;
        tok2slot[i] = slot;
    }
}

// ================= MAIN PATH =================
// ALL weight conversions in ONE dispatch (flat grid). (r14 structure, measured
// equal to r13; kept for its 1-barrier/iter form.)
__global__ __launch_bounds__(256) void conv_all_kernel(
    const float* __restrict__ wgs, const float* __restrict__ wus,
    const float* __restrict__ wds, const float* __restrict__ wg,
    const float* __restrict__ wu, const float* __restrict__ wd, u16* __restrict__ Wt_gs,
    u16* __restrict__ Wt_us, u16* __restrict__ Wt_ds, u16* __restrict__ Wt_g,
    u16* __restrict__ Wt_u, u16* __restrict__ Wt_d) {
    int id = blockIdx.x;
    const float* Wm;
    u16* Wtm;
    int K, N, nt, kc;
    if (id < 768) {
        K = 2048; N = 2048;
        int seg = id >> 8, r = id & 255;
        nt = r & 31; kc = r >> 5;
        if (seg == 0) { Wm = wgs; Wtm = Wt_gs; }
        else if (seg == 1) { Wm = wus; Wtm = Wt_us; }
        else { Wm = wds; Wtm = Wt_ds; }
    } else if (id < 4864) {
        K = 2048; N = 1024;
        int r = id - 768;
        int m = r >> 11;
        r &= 2047;
        int e = r >> 7;
        r &= 127;
        nt = r & 15; kc = r >> 4;
        size_t off = (size_t)e * 2048 * 1024;
        if (m == 0) { Wm = wg + off; Wtm = Wt_g + off; }
        else { Wm = wu + off; Wtm = Wt_u + off; }
    } else {
        K = 1024; N = 2048;
        int r = id - 4864;
        int e = r >> 7;
        r &= 127;
        nt = r & 31; kc = r >> 5;
        size_t off = (size_t)e * 1024 * 2048;
        Wm = wd + off; Wtm = Wt_d + off;
    }
    int ksB = K >> 5;
    __shared__ alignas(16) u16 Ls[2][2560];  // 2 x 64 rows x 40 (double buffer)
    int t = threadIdx.x;
    int kr = t >> 3, ng = t & 7;
    int nn = t >> 2, seg2 = t & 3;
    int g = seg2 ^ ((nn >> 2) & 3);
    int wcol = kr ^ (2 * (ng & 3));  // write swizzle
    int sh = (nn >> 3) & 3;          // reader's u32-word unpermute selector
#pragma unroll
    for (int s = 0; s < 8; s++) {
        u16* L = Ls[s & 1];
        int kb = kc * 256 + s * 32;
        const float* src = Wm + (size_t)(kb + kr) * N + nt * 64 + ng * 8;
        float4 f0 = *(const float4*)src;
        float4 f1 = *(const float4*)(src + 4);
        const float* p0 = (const float*)&f0;
        const float* p1 = (const float*)&f1;
#pragma unroll
        for (int l = 0; l < 4; l++) L[(8 * ng + l) * 40 + wcol] = f2b(p0[l]);
#pragma unroll
        for (int l = 0; l < 4; l++) L[(8 * ng + 4 + l) * 40 + wcol] = f2b(p1[l]);
        __syncthreads();
        uint4 q = *(const uint4*)(L + nn * 40 + g * 8);
        u32 t0 = (sh & 1) ? q.y : q.x;
        u32 t1 = (sh & 1) ? q.x : q.y;
        u32 t2 = (sh & 1) ? q.w : q.z;
        u32 t3 = (sh & 1) ? q.z : q.w;
        uint4 o = make_uint4((sh & 2) ? t2 : t0, (sh & 2) ? t3 : t1,
                             (sh & 2) ? t0 : t2, (sh & 2) ? t1 : t3);
        *(uint4*)(Wtm + (size_t)(nt * ksB + (kb >> 5)) * 2048 + t * 8) = o;
    }
}

// merged fused gate+up: M=128, N=128 per matrix, BK=64, 8 waves. (r11/r13
// verified: 219us, 2-phase structural ceiling for this geometry.)
__global__ __launch_bounds__(512, 4) void gemm_gateup(
    const u16* __restrict__ A, const u16* __restrict__ BgS, const u16* __restrict__ BuS,
    const u16* __restrict__ BgR, const u16* __restrict__ BuR, u16* __restrict__ hS,
    u16* __restrict__ hR, const int* __restrict__ counts, const int* __restrict__ offsets,
    const int* __restrict__ list_tok, const int* __restrict__ items) {
    int it = items[item_index(blockIdx.x)];
    if (it < 0) return;
    int routed = (it >> 28) & 1;
    int e = (it >> 20) & 15;
    int m0 = ((it >> 8) & 4095) * 128;
    int yb = it & 255;  // y-panel of 128
    int cnt, base, Nout;
    u16* hout;
    const u16 *BgBase, *BuBase;
    if (routed) {
        cnt = counts[e];
        base = offsets[e];
        Nout = IDIM;
        size_t off = (size_t)e * HDIM * IDIM;
        BgBase = BgR + off;
        BuBase = BuR + off;
        hout = hR;
    } else {
        cnt = TOKENS;
        base = 0;
        Nout = ISH;
        BgBase = BgS;
        BuBase = BuS;
        hout = hS;
    }
    const int nk = HDIM >> 6;  // BK=64 steps
    __shared__ alignas(16) u16 smem[24576];  // As 16KB | Bgs 16KB | Bus 16KB
    u16* As = smem;
    u16* Bgs = smem + 8192;
    u16* Bus = smem + 16384;
    float* us = (float*)smem;  // epilogue reuse (32KB of the 48KB)
    int tid = threadIdx.x;
    int lane = tid & 63, wv = tid >> 6;  // 8 waves
    int wl = wv & 3, mat = wv >> 2;      // mat: 0=gate, 1=up
    int quad = lane >> 4, mr = lane & 15;
    int gk = (tid & 3) ^ ((tid >> 4) & 3);
    int mg0 = min(m0 + (tid >> 2), cnt - 1);
    size_t sr0 = routed ? (size_t)list_tok[base + mg0] : (size_t)mg0;
    const u16* ap0 = A + sr0 * HDIM + gk * 8;  // thread stages A row tid>>2
    size_t bstr = (size_t)(HDIM >> 5) * 2048;  // per-n64-block stride
    int t4 = tid & 255;
    const u16* Bsel = mat ? BuBase : BgBase;
    const u16* bsrc0 = Bsel + (size_t)(2 * yb) * bstr + (size_t)t4 * 8;  // h=0
    const u16* bsrc1 = bsrc0 + bstr;                                     // h=1
    u16* bb = mat ? Bus : Bgs;
    u16* bdst = bb + wl * 512;  // wave-uniform base (+HW lane*16B)
    u16* adst = As + wv * 512;
    int xq = quad ^ ((mr >> 2) & 3);
    f32x4 acc[2][8];
#pragma unroll
    for (int i = 0; i < 2; i++)
#pragma unroll
        for (int j = 0; j < 8; j++) acc[i][j] = (f32x4)0.f;

    for (int ks = 0; ks < nk; ks++) {
        __syncthreads();
        __builtin_amdgcn_global_load_lds(AS1(ap0), AS3(adst), 16, 0, 0);
        __builtin_amdgcn_global_load_lds(AS1(ap0 + 32), AS3(adst + 4096), 16, 0, 0);
        __builtin_amdgcn_global_load_lds(AS1(bsrc0), AS3(bdst), 16, 0, 0);
        __builtin_amdgcn_global_load_lds(AS1(bsrc0 + 2048), AS3(bdst + 2048), 16, 0, 0);
        __builtin_amdgcn_global_load_lds(AS1(bsrc1), AS3(bdst + 4096), 16, 0, 0);
        __builtin_amdgcn_global_load_lds(AS1(bsrc1 + 2048), AS3(bdst + 6144), 16, 0, 0);
        ap0 += 64;
        bsrc0 += 4096;
        bsrc1 += 4096;
        __syncthreads();
#pragma unroll
        for (int c = 0; c < 2; c++) {
            short8 a0 = *(const short8*)(As + c * 4096 + ((32 * wl + mr) * 4 + xq) * 8);
            short8 a1 = *(const short8*)(As + c * 4096 + ((32 * wl + 16 + mr) * 4 + xq) * 8);
#pragma unroll
            for (int j = 0; j < 8; j++) {
                int h = j >> 2, jj = j & 3;
                short8 b = *(const short8*)(bb + h * 4096 + c * 2048 +
                                            (64 * jj + mr * 4 + xq) * 8);
                acc[0][j] = __builtin_amdgcn_mfma_f32_16x16x32_bf16(a0, b, acc[0][j], 0, 0, 0);
                acc[1][j] = __builtin_amdgcn_mfma_f32_16x16x32_bf16(a1, b, acc[1][j], 0, 0, 0);
            }
        }
    }
    // epilogue: two half-passes of 64 cols through the 32KB us buffer.
#pragma unroll
    for (int p = 0; p < 2; p++) {
        __syncthreads();
        if (mat == 1) {
#pragma unroll
            for (int i = 0; i < 2; i++)
#pragma unroll
                for (int jj = 0; jj < 4; jj++)
#pragma unroll
                    for (int r = 0; r < 4; r++) {
                        int row = 32 * wl + 16 * i + quad * 4 + r;
                        us[row * 64 + 16 * jj + mr] = acc[i][4 * p + jj][r];
                    }
        }
        __syncthreads();
        if (mat == 0) {
#pragma unroll
            for (int i = 0; i < 2; i++)
#pragma unroll
                for (int jj = 0; jj < 4; jj++)
#pragma unroll
                    for (int r = 0; r < 4; r++) {
                        int row = 32 * wl + 16 * i + quad * 4 + r;
                        int m = m0 + row;
                        if (m < cnt) {
                            float gv = acc[i][4 * p + jj][r];
                            float uv = us[row * 64 + 16 * jj + mr];
                            float h = gv / (1.f + expf(-gv)) * uv;
                            int n = yb * 128 + p * 64 + 16 * jj + mr;
                            hout[(size_t)(base + m) * Nout + n] = f2b(h);
                        }
                    }
        }
    }
}

// merged down GEMM: M=256, N=128, BK=64, 8 waves (512 threads). (r13 verified)
__global__ __launch_bounds__(512, 4) void gemm_down(
    const u16* __restrict__ hS, const u16* __restrict__ hR, const u16* __restrict__ BdS,
    const u16* __restrict__ BdR, float* __restrict__ out, float* __restrict__ rd,
    const int* __restrict__ counts, const int* __restrict__ offsets,
    const int* __restrict__ items) {
    int it = items[item_index(blockIdx.x)];
    if (it < 0) return;
    int routed = (it >> 28) & 1;
    int e = (it >> 20) & 15;
    int m0 = ((it >> 8) & 4095) * 256;
    int yb = it & 255;  // y-panel of 128
    int cnt, base, Kd;
    const u16 *A, *B;
    float* outp;
    if (routed) {
        cnt = counts[e];
        base = offsets[e];
        Kd = IDIM;
        A = hR;
        B = BdR + (size_t)e * IDIM * HDIM;
        outp = rd;
    } else {
        cnt = TOKENS;
        base = 0;
        Kd = ISH;
        A = hS;
        B = BdS;
        outp = out;
    }
    int nk = Kd >> 6;  // BK=64
    __shared__ alignas(16) u16 As[2 * 8192];  // 32KB: chunk c at c*8192 (256r x 32k)
    __shared__ alignas(16) u16 Bs[2 * 4096];  // 16KB: half h at h*4096, chunk c +c*2048
    int tid = threadIdx.x;
    int lane = tid & 63, wv = tid >> 6;  // 8 waves
    int wl = wv & 3, nh = wv >> 2;       // m-group / n-half
    int quad = lane >> 4, mr = lane & 15;
    int gk = (tid & 3) ^ ((tid >> 4) & 3);
    int mg0 = base + min(m0 + (tid >> 2), cnt - 1);
    int mg1 = base + min(m0 + 128 + (tid >> 2), cnt - 1);
    const u16* ap0 = A + (size_t)mg0 * Kd + gk * 8;
    const u16* ap1 = A + (size_t)mg1 * Kd + gk * 8;
    size_t bstr = (size_t)(Kd >> 5) * 2048;
    int grp = tid >> 8;  // n-half this thread stages (wave-uniform)
    int t4 = tid & 255;
    const u16* bp = B + (size_t)(2 * yb + grp) * bstr + (size_t)t4 * 8;
    u16* bdst = Bs + grp * 4096 + wl * 512;  // wave-uniform base
    int xq = quad ^ ((mr >> 2) & 3);
    f32x4 acc[4][4];
#pragma unroll
    for (int i = 0; i < 4; i++)
#pragma unroll
        for (int j = 0; j < 4; j++) acc[i][j] = (f32x4)0.f;

    for (int ks = 0; ks < nk; ks++) {
        __syncthreads();
        __builtin_amdgcn_global_load_lds(AS1(ap0), AS3(As + wv * 512), 16, 0, 0);
        __builtin_amdgcn_global_load_lds(AS1(ap0 + 32), AS3(As + 8192 + wv * 512), 16, 0, 0);
        __builtin_amdgcn_global_load_lds(AS1(ap1), AS3(As + 4096 + wv * 512), 16, 0, 0);
        __builtin_amdgcn_global_load_lds(AS1(ap1 + 32), AS3(As + 12288 + wv * 512), 16, 0, 0);
        __builtin_amdgcn_global_load_lds(AS1(bp), AS3(bdst), 16, 0, 0);
        __builtin_amdgcn_global_load_lds(AS1(bp + 2048), AS3(bdst + 2048), 16, 0, 0);
        ap0 += 64; ap1 += 64; bp += 4096;
        __syncthreads();
#pragma unroll
        for (int c = 0; c < 2; c++) {
            short8 a0 = *(const short8*)(As + c * 8192 + ((64 * wl + 0 + mr) * 4 + xq) * 8);
            short8 a1 = *(const short8*)(As + c * 8192 + ((64 * wl + 16 + mr) * 4 + xq) * 8);
            short8 a2 = *(const short8*)(As + c * 8192 + ((64 * wl + 32 + mr) * 4 + xq) * 8);
            short8 a3 = *(const short8*)(As + c * 8192 + ((64 * wl + 48 + mr) * 4 + xq) * 8);
#pragma unroll
            for (int j = 0; j < 4; j++) {
                short8 b = *(const short8*)(Bs + nh * 4096 + c * 2048 +
                                            (64 * j + mr * 4 + xq) * 8);
                acc[0][j] = __builtin_amdgcn_mfma_f32_16x16x32_bf16(a0, b, acc[0][j], 0, 0, 0);
                acc[1][j] = __builtin_amdgcn_mfma_f32_16x16x32_bf16(a1, b, acc[1][j], 0, 0, 0);
                acc[2][j] = __builtin_amdgcn_mfma_f32_16x16x32_bf16(a2, b, acc[2][j], 0, 0, 0);
                acc[3][j] = __builtin_amdgcn_mfma_f32_16x16x32_bf16(a3, b, acc[3][j], 0, 0, 0);
            }
        }
    }

#pragma unroll
    for (int i = 0; i < 4; i++)
#pragma unroll
        for (int j = 0; j < 4; j++)
#pragma unroll
            for (int r = 0; r < 4; r++) {
                int m = m0 + 64 * wl + 16 * i + quad * 4 + r;
                if (m >= cnt) continue;
                int n = yb * 128 + nh * 64 + 16 * j + mr;
                float v = acc[i][j][r];
                if (routed) {
                    outp[(size_t)(base + m) * HDIM + n] = v;  // per-slot, no atomics
                } else {
                    outp[(size_t)m * HDIM + n] = 0.1f * v;
                }
            }
}

// ---------------- combine: out[t] += w0*rd[slot0] + w1*rd[slot1] --------------
// 2 tokens per block (2048 blocks).
__global__ __launch_bounds__(256) void combine_kernel(float* __restrict__ out,
                                                      const float* __restrict__ rd,
                                                      const int* __restrict__ tok2slot,
                                                      const float* __restrict__ top_w) {
#pragma unroll
    for (int tt = 0; tt < 2; tt++) {
        int t = blockIdx.x * 2 + tt;
        int s0 = tok2slot[2 * t], s1 = tok2slot[2 * t + 1];
        float w0 = top_w[2 * t], w1 = top_w[2 * t + 1];
        const float4* r0 = (const float4*)(rd + (size_t)s0 * HDIM);
        const float4* r1 = (const float4*)(rd + (size_t)s1 * HDIM);
        float4* op = (float4*)(out + (size_t)t * HDIM);
#pragma unroll
        for (int k = 0; k < 2; k++) {
            int c = threadIdx.x + k * 256;
            float4 o = op[c];
            float4 a = r0[c];
            float4 b = r1[c];
            o.x += w0 * a.x + w1 * b.x;
            o.y += w0 * a.y + w1 * b.y;
            o.z += w0 * a.z + w1 * b.z;
            o.w += w0 * a.w + w1 * b.w;
            op[c] = o;
        }
    }
}

extern "C" void kernel_launch(void* const* d_in, const int* in_sizes, int n_in,
                              void* d_out, int out_size, void* d_ws, size_t ws_size,
                              hipStream_t stream) {
    const float* x = (const float*)d_in[0];
    const float* cent = (const float*)d_in[1];
    const float* bias = (const float*)d_in[2];
    const float* wgs = (const float*)d_in[3];
    const float* wus = (const float*)d_in[4];
    const float* wds = (const float*)d_in[5];
    const float* wg = (const float*)d_in[6];
    const float* wu = (const float*)d_in[7];
    const float* wd = (const float*)d_in[8];
    float* out = (float*)d_out;
    char* ws = (char*)d_ws;

    size_t off_wtgs = 0;
    size_t off_wtus = off_wtgs + (size_t)HDIM * ISH * 2;
    size_t off_wtds = off_wtus + (size_t)HDIM * ISH * 2;
    size_t off_wtg = off_wtds + (size_t)ISH * HDIM * 2;
    size_t off_wtu = off_wtg + (size_t)NEXP * HDIM * IDIM * 2;
    size_t off_wtd = off_wtu + (size_t)NEXP * HDIM * IDIM * 2;
    size_t off_xbf = off_wtd + (size_t)NEXP * IDIM * HDIM * 2;
    size_t off_hsh = off_xbf + (size_t)TOKENS * HDIM * 2;
    size_t off_hrt = off_hsh + (size_t)TOKENS * ISH * 2;
    size_t off_meta = off_hrt + (size_t)2 * TOKENS * IDIM * 2;
    size_t need = off_meta + (1 << 20);
    if (ws_size < need) return;  // main path verified present in round 2

    u16* Wt_gs = (u16*)(ws + off_wtgs);
    u16* Wt_us = (u16*)(ws + off_wtus);
    u16* Wt_ds = (u16*)(ws + off_wtds);
    u16* Wt_g = (u16*)(ws + off_wtg);
    u16* Wt_u = (u16*)(ws + off_wtu);
    u16* Wt_d = (u16*)(ws + off_wtd);
    u16* x_bf = (u16*)(ws + off_xbf);
    u16* h_sh = (u16*)(ws + off_hsh);
    u16* h_rt = (u16*)(ws + off_hrt);
    // rd (67 MB, f32 [8192][2048]) at off_wtg: overlaps routed gate/up weights
    // only; their last reader (merged gateup) completes before gemm_down writes
    // rd. conv_all rewrites the weights next iteration.
    float* rd = (float*)(ws + off_wtg);
    int* counts = (int*)(ws + off_meta);
    int* offsets = counts + 16;
    int* itemsGU = offsets + 16;
    int* itemsD = itemsGU + GUITEMS;
    int* tok2slot = itemsD + DITEMS;
    int* top_e = tok2slot + 2 * TOKENS;
    float* top_w = (float*)(top_e + 2 * TOKENS);
    int* list_tok = (int*)(top_w + 2 * TOKENS);

    route_kernel<<<TOKENS / 8, 512, 0, stream>>>(x, cent, bias, x_bf, top_e, top_w);
    build_kernel<<<1, 1024, 0, stream>>>(top_e, top_w, counts, offsets, itemsGU, itemsD,
                                         list_tok, tok2slot);
    conv_all_kernel<<<6912, 256, 0, stream>>>(wgs, wus, wds, wg, wu, wd, Wt_gs, Wt_us,
                                              Wt_ds, Wt_g, Wt_u, Wt_d);
    gemm_gateup<<<GUITEMS, 512, 0, stream>>>(x_bf, Wt_gs, Wt_us, Wt_g, Wt_u, h_sh, h_rt,
                                             counts, offsets, list_tok, itemsGU);
    gemm_down<<<DITEMS, 512, 0, stream>>>(h_sh, h_rt, Wt_ds, Wt_d, out, rd, counts,
                                          offsets, itemsD);
    combine_kernel<<<TOKENS / 2, 256, 0, stream>>>(out, rd, tok2slot, top_w);
}